// Round 1
// baseline (1093.923 us; speedup 1.0000x reference)
//
#include <hip/hip_runtime.h>
#include <stdint.h>

#define NA 9
#define HH 50
#define WW 50
#define NPROP (HH*WW*NA)      // 22500
#define NSORT 32768
#define CHUNK 4096
#define PRE_NMS 4000
#define POST_NMS 300
#define NMS_T 0.7f
#define FSTRIDE 16.0f

__device__ __forceinline__ uint32_t f32_ord(float s) {
    uint32_t u = __float_as_uint(s);
    return (u & 0x80000000u) ? ~u : (u | 0x80000000u);
}

// ---------------------------------------------------------------------------
// Kernel 1: decode proposals + build sort keys (pad to NSORT with key=0)
// ---------------------------------------------------------------------------
__global__ void prep_kernel(const float* __restrict__ scores,
                            const float* __restrict__ deltas,
                            const float* __restrict__ im_info,
                            const float* __restrict__ anchors,
                            unsigned long long* __restrict__ keys,
                            float* __restrict__ boxes, int B) {
    int t = blockIdx.x * blockDim.x + threadIdx.x;
    int b = t / NSORT;
    int i = t % NSORT;
    if (b >= B) return;
    if (i >= NPROP) { keys[t] = 0ull; return; }

    int a   = i % NA;
    int pos = i / NA;          // h*W + w
    int w   = pos % WW;
    int h   = pos / WW;

    float score = scores[((size_t)b*2*NA + NA + a)*(HH*WW) + pos];
    keys[t] = ((unsigned long long)f32_ord(score) << 32)
            | (unsigned long long)(0xFFFFFFFFu - (uint32_t)i);

    float ax1 = anchors[a*4+0], ay1 = anchors[a*4+1];
    float ax2 = anchors[a*4+2], ay2 = anchors[a*4+3];
    float sx = (float)w * FSTRIDE, sy = (float)h * FSTRIDE;
    float x1 = ax1 + sx, y1 = ay1 + sy, x2 = ax2 + sx, y2 = ay2 + sy;
    float bw = x2 - x1 + 1.0f;
    float bh = y2 - y1 + 1.0f;
    float cx = x1 + 0.5f * bw;
    float cy = y1 + 0.5f * bh;

    const float* dp = deltas + (size_t)b*4*NA*(HH*WW);
    float dx = dp[(4*a+0)*(HH*WW)+pos];
    float dy = dp[(4*a+1)*(HH*WW)+pos];
    float dw = dp[(4*a+2)*(HH*WW)+pos];
    float dh = dp[(4*a+3)*(HH*WW)+pos];

    float pcx = dx * bw + cx;
    float pcy = dy * bh + cy;
    float pw  = expf(dw) * bw;
    float ph  = expf(dh) * bh;

    float wmax = im_info[b*3+1] - 1.0f;
    float hmax = im_info[b*3+0] - 1.0f;
    float px1 = fminf(fmaxf(pcx - 0.5f*pw, 0.0f), wmax);
    float py1 = fminf(fmaxf(pcy - 0.5f*ph, 0.0f), hmax);
    float px2 = fminf(fmaxf(pcx + 0.5f*pw, 0.0f), wmax);
    float py2 = fminf(fmaxf(pcy + 0.5f*ph, 0.0f), hmax);

    float* bo = boxes + (size_t)(b*NPROP + i)*4;
    bo[0]=px1; bo[1]=py1; bo[2]=px2; bo[3]=py2;
}

// ---------------------------------------------------------------------------
// Kernel 2: bitonic local sort of CHUNK-element chunks (stages k=2..CHUNK).
// Direction per standard network with FINAL DESCENDING: desc iff (gi & k)==0.
// Each block sorts its own chunk in-place (no cross-chunk access -> safe).
// ---------------------------------------------------------------------------
__global__ __launch_bounds__(256) void sort_local_kernel(unsigned long long* __restrict__ keys) {
    __shared__ unsigned long long sk[CHUNK];
    int chunk = blockIdx.x;              // 8 chunks per image
    int cbase = (chunk & 7) * CHUNK;     // base within the image's 32768 array
    unsigned long long* gb = keys + (size_t)chunk * CHUNK;
    int tid = threadIdx.x;

    for (int e = tid; e < CHUNK; e += 256) sk[e] = gb[e];
    __syncthreads();

    for (int k = 2; k <= CHUNK; k <<= 1) {
        for (int j = k >> 1; j > 0; j >>= 1) {
            for (int p = tid; p < CHUNK/2; p += 256) {
                int i = ((p & ~(j-1)) << 1) | (p & (j-1));
                int l = i | j;
                bool desc = (((cbase + i) & k) == 0);
                unsigned long long x = sk[i], y = sk[l];
                if ((x < y) == desc) { sk[i] = y; sk[l] = x; }
            }
            __syncthreads();
        }
    }
    for (int e = tid; e < CHUNK; e += 256) gb[e] = sk[e];
}

// ---------------------------------------------------------------------------
// Kernel 3 (x3): bitonic merge stage k = CHUNK<<NCROSS.
// Cross-chunk steps (j = k/2 .. CHUNK) are computed as a min/max tree over
// 2^NCROSS partner reads (directions are chunk-uniform since j >= CHUNK),
// then the in-chunk cascade (j = CHUNK/2 .. 1) runs in LDS.
// Reads src, writes dst (ping-pong: avoids intra-kernel cross-block races).
// ---------------------------------------------------------------------------
template<int NCROSS>
__global__ __launch_bounds__(256) void merge_kernel(const unsigned long long* __restrict__ src,
                                                    unsigned long long* __restrict__ dst) {
    __shared__ unsigned long long sk[CHUNK];
    const int K = CHUNK << NCROSS;
    int chunk = blockIdx.x;
    int img   = chunk >> 3;
    int cbase = (chunk & 7) * CHUNK;
    const unsigned long long* ib = src + (size_t)img * NSORT;
    int tid = threadIdx.x;
    const bool desc = ((cbase & K) == 0);

    for (int e = tid; e < CHUNK; e += 256) {
        int gi = cbase + e;
        unsigned long long v[1 << NCROSS];
        #pragma unroll
        for (int s = 0; s < (1 << NCROSS); ++s) {
            int off = 0;
            #pragma unroll
            for (int t = 0; t < NCROSS; ++t)
                if (s & (1 << t)) off ^= (K >> (t+1));
            v[s] = ib[gi ^ off];
        }
        #pragma unroll
        for (int t = 0; t < NCROSS; ++t) {
            const int J = K >> (t+1);
            bool mx = desc ^ ((cbase & J) != 0);   // chunk-uniform (J >= CHUNK)
            #pragma unroll
            for (int s = 0; s < (1 << NCROSS); ++s) {
                if ((s & ((2 << t) - 1)) == 0) {
                    unsigned long long a = v[s], b = v[s | (1 << t)];
                    bool agtb = a > b;
                    v[s] = (agtb == mx) ? a : b;
                }
            }
        }
        sk[e] = v[0];
    }
    __syncthreads();

    for (int j = CHUNK >> 1; j > 0; j >>= 1) {
        for (int p = tid; p < CHUNK/2; p += 256) {
            int i = ((p & ~(j-1)) << 1) | (p & (j-1));
            int l = i | j;
            unsigned long long x = sk[i], y = sk[l];
            if ((x < y) == desc) { sk[i] = y; sk[l] = x; }
        }
        __syncthreads();
    }
    unsigned long long* ob = dst + (size_t)img * NSORT + cbase;
    for (int e = tid; e < CHUNK; e += 256) ob[e] = sk[e];
}

// ---------------------------------------------------------------------------
// Kernel 4: greedy sequential NMS on the top-4000, exact reference semantics.
// One block per image, boxes staged in LDS (~84KB).
// ---------------------------------------------------------------------------
__global__ __launch_bounds__(256) void nms_kernel(const unsigned long long* __restrict__ keys,
                                                  const float* __restrict__ boxes,
                                                  float* __restrict__ out) {
    __shared__ float bx1[PRE_NMS], by1[PRE_NMS], bx2[PRE_NMS], by2[PRE_NMS], barea[PRE_NMS];
    __shared__ unsigned char supp[PRE_NMS];
    __shared__ int kc;
    int b = blockIdx.x;
    int tid = threadIdx.x;

    for (int t = tid; t < PRE_NMS; t += 256) {
        unsigned long long key = keys[(size_t)b*NSORT + t];
        uint32_t idx = 0xFFFFFFFFu - (uint32_t)(key & 0xFFFFFFFFull);
        const float* bo = boxes + (size_t)(b*NPROP + (int)idx)*4;
        float x1 = bo[0], y1 = bo[1], x2 = bo[2], y2 = bo[3];
        bx1[t]=x1; by1[t]=y1; bx2[t]=x2; by2[t]=y2;
        barea[t] = (x2-x1+1.0f)*(y2-y1+1.0f);
        supp[t] = 0;
    }
    // init all output rows to [b, 0,0,0,0]
    for (int r = tid; r < POST_NMS; r += 256) {
        float* o = out + (size_t)(b*POST_NMS + r)*5;
        o[0] = (float)b; o[1]=0.0f; o[2]=0.0f; o[3]=0.0f; o[4]=0.0f;
    }
    if (tid == 0) kc = 0;
    __syncthreads();

    for (int i = 0; i < PRE_NMS; ++i) {
        if (supp[i]) continue;            // uniform branch (LDS broadcast)
        if (tid == 0) {
            int r = kc;                   // r < POST_NMS guaranteed (break below)
            float* o = out + (size_t)(b*POST_NMS + r)*5;
            o[0]=(float)b; o[1]=bx1[i]; o[2]=by1[i]; o[3]=bx2[i]; o[4]=by2[i];
            kc = r + 1;
        }
        __syncthreads();
        if (kc >= POST_NMS) break;        // uniform
        float ix1=bx1[i], iy1=by1[i], ix2=bx2[i], iy2=by2[i], iarea=barea[i];
        for (int j = i + 1 + tid; j < PRE_NMS; j += 256) {
            if (supp[j]) continue;
            float xx1 = fmaxf(ix1, bx1[j]);
            float yy1 = fmaxf(iy1, by1[j]);
            float xx2 = fminf(ix2, bx2[j]);
            float yy2 = fminf(iy2, by2[j]);
            float ww = fmaxf(xx2 - xx1 + 1.0f, 0.0f);
            float hh = fmaxf(yy2 - yy1 + 1.0f, 0.0f);
            float inter = ww * hh;
            float iou = inter / (iarea + barea[j] - inter);
            if (iou > NMS_T) supp[j] = 1;
        }
        __syncthreads();
    }
}

// ---------------------------------------------------------------------------
extern "C" void kernel_launch(void* const* d_in, const int* in_sizes, int n_in,
                              void* d_out, int out_size, void* d_ws, size_t ws_size,
                              hipStream_t stream) {
    (void)n_in; (void)out_size; (void)ws_size;
    const float* scores  = (const float*)d_in[0];
    const float* deltas  = (const float*)d_in[1];
    const float* im_info = (const float*)d_in[2];
    const float* anchors = (const float*)d_in[3];
    float* out = (float*)d_out;

    const int B = in_sizes[0] / (2*NA*HH*WW);   // = 2

    // ws layout: keys0 | keys1 | boxes
    unsigned long long* keys0 = (unsigned long long*)d_ws;
    unsigned long long* keys1 = keys0 + (size_t)B*NSORT;
    float* boxes = (float*)(keys1 + (size_t)B*NSORT);

    int totalPrep = B * NSORT;
    prep_kernel<<<(totalPrep + 255)/256, 256, 0, stream>>>(scores, deltas, im_info, anchors,
                                                           keys0, boxes, B);
    sort_local_kernel<<<B*8, 256, 0, stream>>>(keys0);
    merge_kernel<1><<<B*8, 256, 0, stream>>>(keys0, keys1);   // k = 8192
    merge_kernel<2><<<B*8, 256, 0, stream>>>(keys1, keys0);   // k = 16384
    merge_kernel<3><<<B*8, 256, 0, stream>>>(keys0, keys1);   // k = 32768
    nms_kernel<<<B, 256, 0, stream>>>(keys1, boxes, out);
}

// Round 2
// 334.995 us; speedup vs baseline: 3.2655x; 3.2655x over previous
//
#include <hip/hip_runtime.h>
#include <stdint.h>

#define NA 9
#define HH 50
#define WW 50
#define NPROP (HH*WW*NA)      // 22500
#define NSORT 32768
#define CHUNK 4096
#define PRE_NMS 4000
#define POST_NMS 300
#define NWORDS 63             // ceil(4000/64)
#define NMS_T 0.7f
#define FSTRIDE 16.0f

__device__ __forceinline__ uint32_t f32_ord(float s) {
    uint32_t u = __float_as_uint(s);
    return (u & 0x80000000u) ? ~u : (u | 0x80000000u);
}

// ---------------------------------------------------------------------------
// Kernel 1: decode proposals + build sort keys (pad to NSORT with key=0)
// ---------------------------------------------------------------------------
__global__ void prep_kernel(const float* __restrict__ scores,
                            const float* __restrict__ deltas,
                            const float* __restrict__ im_info,
                            const float* __restrict__ anchors,
                            unsigned long long* __restrict__ keys,
                            float* __restrict__ boxes, int B) {
    int t = blockIdx.x * blockDim.x + threadIdx.x;
    int b = t / NSORT;
    int i = t % NSORT;
    if (b >= B) return;
    if (i >= NPROP) { keys[t] = 0ull; return; }

    int a   = i % NA;
    int pos = i / NA;          // h*W + w
    int w   = pos % WW;
    int h   = pos / WW;

    float score = scores[((size_t)b*2*NA + NA + a)*(HH*WW) + pos];
    keys[t] = ((unsigned long long)f32_ord(score) << 32)
            | (unsigned long long)(0xFFFFFFFFu - (uint32_t)i);

    float ax1 = anchors[a*4+0], ay1 = anchors[a*4+1];
    float ax2 = anchors[a*4+2], ay2 = anchors[a*4+3];
    float sx = (float)w * FSTRIDE, sy = (float)h * FSTRIDE;
    float x1 = ax1 + sx, y1 = ay1 + sy, x2 = ax2 + sx, y2 = ay2 + sy;
    float bw = x2 - x1 + 1.0f;
    float bh = y2 - y1 + 1.0f;
    float cx = x1 + 0.5f * bw;
    float cy = y1 + 0.5f * bh;

    const float* dp = deltas + (size_t)b*4*NA*(HH*WW);
    float dx = dp[(4*a+0)*(HH*WW)+pos];
    float dy = dp[(4*a+1)*(HH*WW)+pos];
    float dw = dp[(4*a+2)*(HH*WW)+pos];
    float dh = dp[(4*a+3)*(HH*WW)+pos];

    float pcx = dx * bw + cx;
    float pcy = dy * bh + cy;
    float pw  = expf(dw) * bw;
    float ph  = expf(dh) * bh;

    float wmax = im_info[b*3+1] - 1.0f;
    float hmax = im_info[b*3+0] - 1.0f;
    float px1 = fminf(fmaxf(pcx - 0.5f*pw, 0.0f), wmax);
    float py1 = fminf(fmaxf(pcy - 0.5f*ph, 0.0f), hmax);
    float px2 = fminf(fmaxf(pcx + 0.5f*pw, 0.0f), wmax);
    float py2 = fminf(fmaxf(pcy + 0.5f*ph, 0.0f), hmax);

    float* bo = boxes + (size_t)(b*NPROP + i)*4;
    bo[0]=px1; bo[1]=py1; bo[2]=px2; bo[3]=py2;
}

// ---------------------------------------------------------------------------
// Kernel 2: bitonic local sort of CHUNK-element chunks (stages k=2..CHUNK).
// ---------------------------------------------------------------------------
__global__ __launch_bounds__(256) void sort_local_kernel(unsigned long long* __restrict__ keys) {
    __shared__ unsigned long long sk[CHUNK];
    int chunk = blockIdx.x;
    int cbase = (chunk & 7) * CHUNK;
    unsigned long long* gb = keys + (size_t)chunk * CHUNK;
    int tid = threadIdx.x;

    for (int e = tid; e < CHUNK; e += 256) sk[e] = gb[e];
    __syncthreads();

    for (int k = 2; k <= CHUNK; k <<= 1) {
        for (int j = k >> 1; j > 0; j >>= 1) {
            for (int p = tid; p < CHUNK/2; p += 256) {
                int i = ((p & ~(j-1)) << 1) | (p & (j-1));
                int l = i | j;
                bool desc = (((cbase + i) & k) == 0);
                unsigned long long x = sk[i], y = sk[l];
                if ((x < y) == desc) { sk[i] = y; sk[l] = x; }
            }
            __syncthreads();
        }
    }
    for (int e = tid; e < CHUNK; e += 256) gb[e] = sk[e];
}

// ---------------------------------------------------------------------------
// Kernel 3 (x3): bitonic merge stage k = CHUNK<<NCROSS (ping-pong src->dst).
// ---------------------------------------------------------------------------
template<int NCROSS>
__global__ __launch_bounds__(256) void merge_kernel(const unsigned long long* __restrict__ src,
                                                    unsigned long long* __restrict__ dst) {
    __shared__ unsigned long long sk[CHUNK];
    const int K = CHUNK << NCROSS;
    int chunk = blockIdx.x;
    int img   = chunk >> 3;
    int cbase = (chunk & 7) * CHUNK;
    const unsigned long long* ib = src + (size_t)img * NSORT;
    int tid = threadIdx.x;
    const bool desc = ((cbase & K) == 0);

    for (int e = tid; e < CHUNK; e += 256) {
        int gi = cbase + e;
        unsigned long long v[1 << NCROSS];
        #pragma unroll
        for (int s = 0; s < (1 << NCROSS); ++s) {
            int off = 0;
            #pragma unroll
            for (int t = 0; t < NCROSS; ++t)
                if (s & (1 << t)) off ^= (K >> (t+1));
            v[s] = ib[gi ^ off];
        }
        #pragma unroll
        for (int t = 0; t < NCROSS; ++t) {
            const int J = K >> (t+1);
            bool mx = desc ^ ((cbase & J) != 0);
            #pragma unroll
            for (int s = 0; s < (1 << NCROSS); ++s) {
                if ((s & ((2 << t) - 1)) == 0) {
                    unsigned long long a = v[s], b = v[s | (1 << t)];
                    bool agtb = a > b;
                    v[s] = (agtb == mx) ? a : b;
                }
            }
        }
        sk[e] = v[0];
    }
    __syncthreads();

    for (int j = CHUNK >> 1; j > 0; j >>= 1) {
        for (int p = tid; p < CHUNK/2; p += 256) {
            int i = ((p & ~(j-1)) << 1) | (p & (j-1));
            int l = i | j;
            unsigned long long x = sk[i], y = sk[l];
            if ((x < y) == desc) { sk[i] = y; sk[l] = x; }
        }
        __syncthreads();
    }
    unsigned long long* ob = dst + (size_t)img * NSORT + cbase;
    for (int e = tid; e < CHUNK; e += 256) ob[e] = sk[e];
}

// ---------------------------------------------------------------------------
// Kernel 4: gather top-4000 boxes in sorted order -> gboxes (float4)
// ---------------------------------------------------------------------------
__global__ __launch_bounds__(256) void gather_kernel(const unsigned long long* __restrict__ keys,
                                                     const float* __restrict__ boxes,
                                                     float4* __restrict__ gboxes, int B) {
    int t = blockIdx.x * blockDim.x + threadIdx.x;
    if (t >= B * PRE_NMS) return;
    int b = t / PRE_NMS;
    int r = t % PRE_NMS;
    unsigned long long key = keys[(size_t)b*NSORT + r];
    uint32_t idx = 0xFFFFFFFFu - (uint32_t)(key & 0xFFFFFFFFull);
    gboxes[t] = ((const float4*)boxes)[(size_t)b*NPROP + idx];
}

// ---------------------------------------------------------------------------
// Kernel 5: suppression bit-matrix. mask[(b*4000+i)*64 + cb] = u64 of
// "box i suppresses box j" bits for j in [cb*64, cb*64+64), only j>i set.
// Grid: (63 row-blocks, 63 col-blocks, B), 64 threads; cb<rb blocks skip.
// ---------------------------------------------------------------------------
__global__ __launch_bounds__(64) void mask_kernel(const float4* __restrict__ gboxes,
                                                  unsigned long long* __restrict__ mask) {
    int rb = blockIdx.x, cb = blockIdx.y, b = blockIdx.z;
    if (cb < rb) return;
    __shared__ float cx1[64], cy1[64], cx2[64], cy2[64], car[64];
    int tid = threadIdx.x;

    int j0 = cb*64 + tid;
    float4 cbx = (j0 < PRE_NMS) ? gboxes[(size_t)b*PRE_NMS + j0]
                                : make_float4(0.f,0.f,0.f,0.f);
    cx1[tid]=cbx.x; cy1[tid]=cbx.y; cx2[tid]=cbx.z; cy2[tid]=cbx.w;
    car[tid]=(cbx.z-cbx.x+1.0f)*(cbx.w-cbx.y+1.0f);
    __syncthreads();

    int i = rb*64 + tid;
    if (i >= PRE_NMS) return;
    float4 rbx = gboxes[(size_t)b*PRE_NMS + i];
    float ix1=rbx.x, iy1=rbx.y, ix2=rbx.z, iy2=rbx.w;
    float iarea=(ix2-ix1+1.0f)*(iy2-iy1+1.0f);

    unsigned long long bits = 0;
    #pragma unroll 16
    for (int k = 0; k < 64; ++k) {
        int j = cb*64 + k;
        float xx1 = fmaxf(ix1, cx1[k]);
        float yy1 = fmaxf(iy1, cy1[k]);
        float xx2 = fminf(ix2, cx2[k]);
        float yy2 = fminf(iy2, cy2[k]);
        float ww = fmaxf(xx2 - xx1 + 1.0f, 0.0f);
        float hh = fmaxf(yy2 - yy1 + 1.0f, 0.0f);
        float inter = ww * hh;
        float iou = inter / (iarea + car[k] - inter);
        if ((j > i) & (j < PRE_NMS) & (iou > NMS_T)) bits |= (1ull << k);
    }
    mask[(((size_t)b*PRE_NMS + i) << 6) + cb] = bits;
}

// ---------------------------------------------------------------------------
// Kernel 6: serial greedy scan over the bitmask. 1 wave per image; the
// 4000-bit suppressed state lives distributed: lane l owns boxes l*64..+63.
// ---------------------------------------------------------------------------
__global__ __launch_bounds__(64) void scan_kernel(const unsigned long long* __restrict__ mask,
                                                  const float4* __restrict__ gboxes,
                                                  float* __restrict__ out) {
    __shared__ int keep_idx[POST_NMS];
    int b = blockIdx.x;
    int lane = threadIdx.x;
    unsigned long long supp = 0;
    int kept = 0;

    for (int i = 0; i < PRE_NMS; ++i) {
        int wi = i >> 6, bi = i & 63;
        unsigned long long w = __shfl(supp, wi);       // uniform across lanes
        if (!((w >> bi) & 1ull)) {
            if (lane == 0) keep_idx[kept] = i;
            ++kept;
            if (kept >= POST_NMS) break;
            const unsigned long long* row = mask + (((size_t)b*PRE_NMS + i) << 6);
            unsigned long long m = 0;
            if (lane >= wi && lane < NWORDS) m = row[lane];
            supp |= m;
        }
    }
    __syncthreads();

    for (int r = lane; r < POST_NMS; r += 64) {
        float4 bx = (r < kept) ? gboxes[(size_t)b*PRE_NMS + keep_idx[r]]
                               : make_float4(0.f,0.f,0.f,0.f);
        float* o = out + (size_t)(b*POST_NMS + r)*5;
        o[0]=(float)b; o[1]=bx.x; o[2]=bx.y; o[3]=bx.z; o[4]=bx.w;
    }
}

// ---------------------------------------------------------------------------
extern "C" void kernel_launch(void* const* d_in, const int* in_sizes, int n_in,
                              void* d_out, int out_size, void* d_ws, size_t ws_size,
                              hipStream_t stream) {
    (void)n_in; (void)out_size; (void)ws_size;
    const float* scores  = (const float*)d_in[0];
    const float* deltas  = (const float*)d_in[1];
    const float* im_info = (const float*)d_in[2];
    const float* anchors = (const float*)d_in[3];
    float* out = (float*)d_out;

    const int B = in_sizes[0] / (2*NA*HH*WW);   // = 2

    // ws layout: keys0 | keys1 | boxes | gboxes | mask
    unsigned long long* keys0 = (unsigned long long*)d_ws;
    unsigned long long* keys1 = keys0 + (size_t)B*NSORT;
    float* boxes  = (float*)(keys1 + (size_t)B*NSORT);
    float4* gboxes = (float4*)(boxes + (size_t)B*NPROP*4);
    unsigned long long* mask = (unsigned long long*)(gboxes + (size_t)B*PRE_NMS);

    int totalPrep = B * NSORT;
    prep_kernel<<<(totalPrep + 255)/256, 256, 0, stream>>>(scores, deltas, im_info, anchors,
                                                           keys0, boxes, B);
    sort_local_kernel<<<B*8, 256, 0, stream>>>(keys0);
    merge_kernel<1><<<B*8, 256, 0, stream>>>(keys0, keys1);   // k = 8192
    merge_kernel<2><<<B*8, 256, 0, stream>>>(keys1, keys0);   // k = 16384
    merge_kernel<3><<<B*8, 256, 0, stream>>>(keys0, keys1);   // k = 32768

    gather_kernel<<<(B*PRE_NMS + 255)/256, 256, 0, stream>>>(keys1, boxes, gboxes, B);
    dim3 mgrid(NWORDS, NWORDS, B);
    mask_kernel<<<mgrid, 64, 0, stream>>>(gboxes, mask);
    scan_kernel<<<B, 64, 0, stream>>>(mask, gboxes, out);
}

// Round 7
// 280.371 us; speedup vs baseline: 3.9017x; 1.1948x over previous
//
#include <hip/hip_runtime.h>
#include <stdint.h>

#define NA 9
#define HH 50
#define WW 50
#define NPROP (HH*WW*NA)      // 22500
#define NSORT 32768
#define CHUNK 4096
#define PRE_NMS 4000
#define POST_NMS 300
#define NWORDS 63             // ceil(4000/64)
#define NMS_T 0.7f
#define FSTRIDE 16.0f

typedef unsigned long long ull;

__device__ __forceinline__ uint32_t f32_ord(float s) {
    uint32_t u = __float_as_uint(s);
    return (u & 0x80000000u) ? ~u : (u | 0x80000000u);
}

// ---------------------------------------------------------------------------
// Kernel 1: fused decode + key build + bitonic local sort of one 4096-chunk.
// Grid: B*8 blocks x 1024. Keys built directly in LDS; boxes written global.
// ---------------------------------------------------------------------------
__global__ __launch_bounds__(1024) void prep_sort_kernel(
        const float* __restrict__ scores,
        const float* __restrict__ deltas,
        const float* __restrict__ im_info,
        const float* __restrict__ anchors,
        ull* __restrict__ keys,
        float4* __restrict__ boxes4) {
    __shared__ ull sk[CHUNK];
    int chunk = blockIdx.x;
    int img   = chunk >> 3;
    int cbase = (chunk & 7) * CHUNK;
    int tid = threadIdx.x;

    float wmax = im_info[img*3+1] - 1.0f;
    float hmax = im_info[img*3+0] - 1.0f;

    for (int e = tid; e < CHUNK; e += 1024) {
        int i = cbase + e;
        if (i >= NPROP) { sk[e] = 0ull; continue; }
        int a   = i % NA;
        int pos = i / NA;
        int w   = pos % WW;
        int h   = pos / WW;

        float score = scores[((size_t)img*2*NA + NA + a)*(HH*WW) + pos];
        sk[e] = ((ull)f32_ord(score) << 32) | (ull)(0xFFFFFFFFu - (uint32_t)i);

        float ax1 = anchors[a*4+0], ay1 = anchors[a*4+1];
        float ax2 = anchors[a*4+2], ay2 = anchors[a*4+3];
        float sx = (float)w * FSTRIDE, sy = (float)h * FSTRIDE;
        float x1 = ax1 + sx, y1 = ay1 + sy, x2 = ax2 + sx, y2 = ay2 + sy;
        float bw = x2 - x1 + 1.0f;
        float bh = y2 - y1 + 1.0f;
        float cx = x1 + 0.5f * bw;
        float cy = y1 + 0.5f * bh;

        const float* dp = deltas + (size_t)img*4*NA*(HH*WW);
        float dx = dp[(4*a+0)*(HH*WW)+pos];
        float dy = dp[(4*a+1)*(HH*WW)+pos];
        float dw = dp[(4*a+2)*(HH*WW)+pos];
        float dh = dp[(4*a+3)*(HH*WW)+pos];

        float pcx = dx * bw + cx;
        float pcy = dy * bh + cy;
        float pw  = expf(dw) * bw;
        float ph  = expf(dh) * bh;

        float px1 = fminf(fmaxf(pcx - 0.5f*pw, 0.0f), wmax);
        float py1 = fminf(fmaxf(pcy - 0.5f*ph, 0.0f), hmax);
        float px2 = fminf(fmaxf(pcx + 0.5f*pw, 0.0f), wmax);
        float py2 = fminf(fmaxf(pcy + 0.5f*ph, 0.0f), hmax);

        boxes4[(size_t)img*NPROP + i] = make_float4(px1, py1, px2, py2);
    }
    __syncthreads();

    for (int k = 2; k <= CHUNK; k <<= 1) {
        for (int j = k >> 1; j > 0; j >>= 1) {
            for (int p = tid; p < CHUNK/2; p += 1024) {
                int i = ((p & ~(j-1)) << 1) | (p & (j-1));
                int l = i | j;
                bool desc = (((cbase + i) & k) == 0);
                ull x = sk[i], y = sk[l];
                if ((x < y) == desc) { sk[i] = y; sk[l] = x; }
            }
            __syncthreads();
        }
    }
    ull* gb = keys + (size_t)chunk * CHUNK;
    for (int e = tid; e < CHUNK; e += 1024) gb[e] = sk[e];
}

// ---------------------------------------------------------------------------
// Kernel 2 (x2): bitonic merge stage k = CHUNK<<NCROSS (ping-pong src->dst).
// ---------------------------------------------------------------------------
template<int NCROSS>
__global__ __launch_bounds__(1024) void merge_kernel(const ull* __restrict__ src,
                                                     ull* __restrict__ dst) {
    __shared__ ull sk[CHUNK];
    const int K = CHUNK << NCROSS;
    int chunk = blockIdx.x;
    int img   = chunk >> 3;
    int cbase = (chunk & 7) * CHUNK;
    const ull* ib = src + (size_t)img * NSORT;
    int tid = threadIdx.x;
    const bool desc = ((cbase & K) == 0);

    for (int e = tid; e < CHUNK; e += 1024) {
        int gi = cbase + e;
        ull v[1 << NCROSS];
        #pragma unroll
        for (int s = 0; s < (1 << NCROSS); ++s) {
            int off = 0;
            #pragma unroll
            for (int t = 0; t < NCROSS; ++t)
                if (s & (1 << t)) off ^= (K >> (t+1));
            v[s] = ib[gi ^ off];
        }
        #pragma unroll
        for (int t = 0; t < NCROSS; ++t) {
            const int J = K >> (t+1);
            bool mx = desc ^ ((cbase & J) != 0);
            #pragma unroll
            for (int s = 0; s < (1 << NCROSS); ++s) {
                if ((s & ((2 << t) - 1)) == 0) {
                    ull a = v[s], b = v[s | (1 << t)];
                    bool agtb = a > b;
                    v[s] = (agtb == mx) ? a : b;
                }
            }
        }
        sk[e] = v[0];
    }
    __syncthreads();

    for (int j = CHUNK >> 1; j > 0; j >>= 1) {
        for (int p = tid; p < CHUNK/2; p += 1024) {
            int i = ((p & ~(j-1)) << 1) | (p & (j-1));
            int l = i | j;
            ull x = sk[i], y = sk[l];
            if ((x < y) == desc) { sk[i] = y; sk[l] = x; }
        }
        __syncthreads();
    }
    ull* ob = dst + (size_t)img * NSORT + cbase;
    for (int e = tid; e < CHUNK; e += 1024) ob[e] = sk[e];
}

// ---------------------------------------------------------------------------
// Kernel 3: final merge stage specialized to chunk 0 (ranks 0..4095) fused
// with the box gather. Chunk 0 of stage k=32768 is an 8-way max over the
// stripes, then the standard 12-pass descending cascade. Grid: B x 1024.
// ---------------------------------------------------------------------------
__global__ __launch_bounds__(1024) void final_merge_gather(const ull* __restrict__ src,
                                                           const float4* __restrict__ boxes4,
                                                           float4* __restrict__ gboxes) {
    __shared__ ull sk[CHUNK];
    int img = blockIdx.x;
    const ull* ib = src + (size_t)img * NSORT;
    int tid = threadIdx.x;

    for (int e = tid; e < CHUNK; e += 1024) {
        ull m = ib[e];
        #pragma unroll
        for (int s = 1; s < 8; ++s) {
            ull v = ib[e + s*CHUNK];
            m = (v > m) ? v : m;
        }
        sk[e] = m;
    }
    __syncthreads();

    for (int j = CHUNK >> 1; j > 0; j >>= 1) {
        for (int p = tid; p < CHUNK/2; p += 1024) {
            int i = ((p & ~(j-1)) << 1) | (p & (j-1));
            int l = i | j;
            ull x = sk[i], y = sk[l];
            if (x < y) { sk[i] = y; sk[l] = x; }   // descending
        }
        __syncthreads();
    }

    for (int e = tid; e < PRE_NMS; e += 1024) {
        uint32_t idx = 0xFFFFFFFFu - (uint32_t)(sk[e] & 0xFFFFFFFFull);
        gboxes[(size_t)img*PRE_NMS + e] = boxes4[(size_t)img*NPROP + idx];
    }
}

// ---------------------------------------------------------------------------
// Kernel 4: suppression bit-matrix (only j>i bits; words cb>=rb written).
// ---------------------------------------------------------------------------
__global__ __launch_bounds__(64) void mask_kernel(const float4* __restrict__ gboxes,
                                                  ull* __restrict__ mask) {
    int rb = blockIdx.x, cb = blockIdx.y, b = blockIdx.z;
    if (cb < rb) return;
    __shared__ float cx1[64], cy1[64], cx2[64], cy2[64], car[64];
    int tid = threadIdx.x;

    int j0 = cb*64 + tid;
    float4 cbx = (j0 < PRE_NMS) ? gboxes[(size_t)b*PRE_NMS + j0]
                                : make_float4(0.f,0.f,0.f,0.f);
    cx1[tid]=cbx.x; cy1[tid]=cbx.y; cx2[tid]=cbx.z; cy2[tid]=cbx.w;
    car[tid]=(cbx.z-cbx.x+1.0f)*(cbx.w-cbx.y+1.0f);
    __syncthreads();

    int i = rb*64 + tid;
    if (i >= PRE_NMS) return;
    float4 rbx = gboxes[(size_t)b*PRE_NMS + i];
    float ix1=rbx.x, iy1=rbx.y, ix2=rbx.z, iy2=rbx.w;
    float iarea=(ix2-ix1+1.0f)*(iy2-iy1+1.0f);

    ull bits = 0;
    #pragma unroll 16
    for (int k = 0; k < 64; ++k) {
        int j = cb*64 + k;
        float xx1 = fmaxf(ix1, cx1[k]);
        float yy1 = fmaxf(iy1, cy1[k]);
        float xx2 = fminf(ix2, cx2[k]);
        float yy2 = fminf(iy2, cy2[k]);
        float ww = fmaxf(xx2 - xx1 + 1.0f, 0.0f);
        float hh = fmaxf(yy2 - yy1 + 1.0f, 0.0f);
        float inter = ww * hh;
        float iou = inter / (iarea + car[k] - inter);
        if ((j > i) & (j < PRE_NMS) & (iou > NMS_T)) bits |= (1ull << k);
    }
    mask[(((size_t)b*PRE_NMS + i) << 6) + cb] = bits;
}

// ---------------------------------------------------------------------------
// Kernel 5: greedy scan with ctz skipping. 1 wave/image; lane l owns the
// 64-candidate window l. Only window broadcasts + kept-row loads are serial.
// ---------------------------------------------------------------------------
__global__ __launch_bounds__(64) void scan_kernel(const ull* __restrict__ mask,
                                                  const float4* __restrict__ gboxes,
                                                  float* __restrict__ out) {
    __shared__ int keep_idx[POST_NMS];
    int b = blockIdx.x;
    int lane = threadIdx.x;
    ull supp = 0;
    if (lane == NWORDS-1) supp = 0xFFFFFFFF00000000ull;  // 3968+32 = 4000
    if (lane >= NWORDS)   supp = ~0ull;
    int kept = 0;
    bool done = false;

    for (int wi = 0; wi < NWORDS && !done; ++wi) {
        ull avail = ~__shfl(supp, wi);
        while (avail) {
            int bi = __builtin_ctzll(avail);
            int i = (wi << 6) + bi;
            if (lane == 0) keep_idx[kept] = i;
            ++kept;
            if (kept >= POST_NMS) { done = true; break; }
            const ull* row = mask + (((size_t)b*PRE_NMS + i) << 6);
            ull m = (lane >= wi && lane < NWORDS) ? row[lane] : 0ull;
            supp |= m;
            ull mw = __shfl(m, wi);
            avail &= ~mw;          // suppress within current window
            avail &= avail - 1;    // clear bit bi (kept)
        }
    }
    __syncthreads();

    for (int r = lane; r < POST_NMS; r += 64) {
        float4 bx = (r < kept) ? gboxes[(size_t)b*PRE_NMS + keep_idx[r]]
                               : make_float4(0.f,0.f,0.f,0.f);
        float* o = out + (size_t)(b*POST_NMS + r)*5;
        o[0]=(float)b; o[1]=bx.x; o[2]=bx.y; o[3]=bx.z; o[4]=bx.w;
    }
}

// ---------------------------------------------------------------------------
extern "C" void kernel_launch(void* const* d_in, const int* in_sizes, int n_in,
                              void* d_out, int out_size, void* d_ws, size_t ws_size,
                              hipStream_t stream) {
    (void)n_in; (void)out_size; (void)ws_size;
    const float* scores  = (const float*)d_in[0];
    const float* deltas  = (const float*)d_in[1];
    const float* im_info = (const float*)d_in[2];
    const float* anchors = (const float*)d_in[3];
    float* out = (float*)d_out;

    const int B = in_sizes[0] / (2*NA*HH*WW);   // = 2

    // ws layout: keys0 | keys1 | boxes4 | gboxes | mask
    ull* keys0 = (ull*)d_ws;
    ull* keys1 = keys0 + (size_t)B*NSORT;
    float4* boxes4 = (float4*)(keys1 + (size_t)B*NSORT);
    float4* gboxes = boxes4 + (size_t)B*NPROP;
    ull* mask = (ull*)(gboxes + (size_t)B*PRE_NMS);

    prep_sort_kernel<<<B*8, 1024, 0, stream>>>(scores, deltas, im_info, anchors,
                                               keys0, boxes4);
    merge_kernel<1><<<B*8, 1024, 0, stream>>>(keys0, keys1);   // k = 8192
    merge_kernel<2><<<B*8, 1024, 0, stream>>>(keys1, keys0);   // k = 16384
    final_merge_gather<<<B, 1024, 0, stream>>>(keys0, boxes4, gboxes);
    dim3 mgrid(NWORDS, NWORDS, B);
    mask_kernel<<<mgrid, 64, 0, stream>>>(gboxes, mask);
    scan_kernel<<<B, 64, 0, stream>>>(mask, gboxes, out);
}

// Round 8
// 256.830 us; speedup vs baseline: 4.2593x; 1.0917x over previous
//
#include <hip/hip_runtime.h>
#include <stdint.h>

#define NA 9
#define HH 50
#define WW 50
#define NPROP (HH*WW*NA)      // 22500
#define PRE_NMS 4000
#define POST_NMS 300
#define NWORDS 63             // ceil(4000/64) suppression words per row
#define ROWSTRIDE 64          // mask row stride in u64 words
#define MROWS 4032            // padded rows per image (63 windows * 64)
#define SORTN 8192            // select-sort capacity (top-4000 + threshold-bucket slack)
#define NMS_T 0.7f
#define FSTRIDE 16.0f

typedef unsigned long long ull;

__device__ __forceinline__ uint32_t f32_ord(float s) {
    uint32_t u = __float_as_uint(s);
    return (u & 0x80000000u) ? ~u : (u | 0x80000000u);
}

// ---------------------------------------------------------------------------
// Kernel 1: decode boxes + build keys + histogram of top-16 key bits.
// ---------------------------------------------------------------------------
__global__ void decode_hist(const float* __restrict__ scores,
                            const float* __restrict__ deltas,
                            const float* __restrict__ im_info,
                            const float* __restrict__ anchors,
                            ull* __restrict__ keys,
                            float4* __restrict__ boxes4,
                            uint32_t* __restrict__ hist, int B) {
    int t = blockIdx.x * blockDim.x + threadIdx.x;
    if (t >= B * NPROP) return;
    int b = t / NPROP;
    int i = t % NPROP;

    int a   = i % NA;
    int pos = i / NA;          // h*W + w
    int w   = pos % WW;
    int h   = pos / WW;

    float score = scores[((size_t)b*2*NA + NA + a)*(HH*WW) + pos];
    ull key = ((ull)f32_ord(score) << 32) | (ull)(0xFFFFFFFFu - (uint32_t)i);
    keys[t] = key;
    atomicAdd(&hist[((uint32_t)b << 16) | (uint32_t)(key >> 48)], 1u);

    float ax1 = anchors[a*4+0], ay1 = anchors[a*4+1];
    float ax2 = anchors[a*4+2], ay2 = anchors[a*4+3];
    float sx = (float)w * FSTRIDE, sy = (float)h * FSTRIDE;
    float x1 = ax1 + sx, y1 = ay1 + sy, x2 = ax2 + sx, y2 = ay2 + sy;
    float bw = x2 - x1 + 1.0f;
    float bh = y2 - y1 + 1.0f;
    float cx = x1 + 0.5f * bw;
    float cy = y1 + 0.5f * bh;

    const float* dp = deltas + (size_t)b*4*NA*(HH*WW);
    float dx = dp[(4*a+0)*(HH*WW)+pos];
    float dy = dp[(4*a+1)*(HH*WW)+pos];
    float dw = dp[(4*a+2)*(HH*WW)+pos];
    float dh = dp[(4*a+3)*(HH*WW)+pos];

    float pcx = dx * bw + cx;
    float pcy = dy * bh + cy;
    float pw  = expf(dw) * bw;
    float ph  = expf(dh) * bh;

    float wmax = im_info[b*3+1] - 1.0f;
    float hmax = im_info[b*3+0] - 1.0f;
    float px1 = fminf(fmaxf(pcx - 0.5f*pw, 0.0f), wmax);
    float py1 = fminf(fmaxf(pcy - 0.5f*ph, 0.0f), hmax);
    float px2 = fminf(fmaxf(pcx + 0.5f*pw, 0.0f), wmax);
    float py2 = fminf(fmaxf(pcy + 0.5f*ph, 0.0f), hmax);

    boxes4[t] = make_float4(px1, py1, px2, py2);
}

// ---------------------------------------------------------------------------
// Kernel 2: one block per image. Find 16-bit threshold bucket from the
// histogram (coarse Hillis-Steele scan + fine serial), compact all keys in
// buckets >= threshold into LDS (M in [4000, ~4100] for random scores;
// SORTN=8192 gives huge slack), bitonic-sort SORTN descending, gather the
// top-4000 boxes in sorted order.
// ---------------------------------------------------------------------------
__global__ __launch_bounds__(1024) void select_sort_gather(
        const ull* __restrict__ keys,
        const uint32_t* __restrict__ hist,
        const float4* __restrict__ boxes4,
        float4* __restrict__ gboxes) {
    __shared__ ull sk[SORTN];          // 64 KB: compact buffer + sort array
    __shared__ int sA[1024], sB[1024]; // coarse sums + scan ping-pong
    __shared__ int nfine[64];
    __shared__ int sSeg, aboveC, thr, lcount;
    int img = blockIdx.x, tid = threadIdx.x;
    const uint32_t* h = hist + ((uint32_t)img << 16);

    // --- Phase A: coarse per-64-bucket sums (vectorized uint4 loads) ---
    {
        const uint4* h4 = (const uint4*)h;
        uint32_t s = 0;
        #pragma unroll
        for (int u = 0; u < 16; ++u) {
            uint4 v = h4[(tid << 4) | u];
            s += v.x + v.y + v.z + v.w;
        }
        sA[tid] = (int)s;
    }
    __syncthreads();
    // cumulative-from-top: cft[t] = sum_{u>=t} coarse[u]
    int* curp = sA; int* nxtp = sB;
    for (int d = 1; d < 1024; d <<= 1) {
        int v = curp[tid] + ((tid + d < 1024) ? curp[tid + d] : 0);
        nxtp[tid] = v;
        __syncthreads();
        int* tmp = curp; curp = nxtp; nxtp = tmp;
    }
    {
        int cftS  = curp[tid];
        int cftS1 = (tid < 1023) ? curp[tid + 1] : 0;
        if (cftS >= PRE_NMS && cftS1 < PRE_NMS) { sSeg = tid; aboveC = cftS1; }
    }
    __syncthreads();
    if (tid < 64) nfine[tid] = (int)h[(sSeg << 6) | tid];
    __syncthreads();
    if (tid == 0) {
        int cum = aboveC;          // count of keys in buckets > current
        int t = sSeg << 6;
        for (int w = 63; w >= 0; --w) {
            int nc = cum + nfine[w];
            if (nc >= PRE_NMS) { t = (sSeg << 6) | w; break; }
            cum = nc;
        }
        thr = t;
        lcount = 0;
    }
    __syncthreads();

    // --- Phase B: compact keys with bucket >= thr into sk ---
    {
        const ull* kb = keys + (size_t)img * NPROP;
        int th = thr;
        for (int i = tid; i < NPROP; i += 1024) {
            ull key = kb[i];
            if ((int)(key >> 48) >= th) {
                int p = atomicAdd(&lcount, 1);
                if (p < SORTN) sk[p] = key;   // overflow impossible for non-degenerate scores
            }
        }
    }
    __syncthreads();
    {
        int M = lcount;
        for (int e = tid; e < SORTN; e += 1024)
            if (e >= M) sk[e] = 0ull;
    }
    __syncthreads();

    // --- Phase C: bitonic sort SORTN descending ---
    for (int k = 2; k <= SORTN; k <<= 1) {
        for (int j = k >> 1; j > 0; j >>= 1) {
            for (int p = tid; p < SORTN/2; p += 1024) {
                int i2 = ((p & ~(j-1)) << 1) | (p & (j-1));
                int l2 = i2 | j;
                bool desc = ((i2 & k) == 0);
                ull x = sk[i2], y = sk[l2];
                if ((x < y) == desc) { sk[i2] = y; sk[l2] = x; }
            }
            __syncthreads();
        }
    }

    // --- Phase D: gather boxes for ranks 0..3999 ---
    for (int e = tid; e < PRE_NMS; e += 1024) {
        uint32_t idx = 0xFFFFFFFFu - (uint32_t)(sk[e] & 0xFFFFFFFFull);
        gboxes[(size_t)img*PRE_NMS + e] = boxes4[(size_t)img*NPROP + idx];
    }
}

// ---------------------------------------------------------------------------
// Kernel 3: suppression bit-matrix (only j>i bits; words cb>=rb written).
// Rows padded to MROWS per image so the scan can prefetch whole windows.
// ---------------------------------------------------------------------------
__global__ __launch_bounds__(64) void mask_kernel(const float4* __restrict__ gboxes,
                                                  ull* __restrict__ mask) {
    int rb = blockIdx.x, cb = blockIdx.y, b = blockIdx.z;
    if (cb < rb) return;
    __shared__ float cx1[64], cy1[64], cx2[64], cy2[64], car[64];
    int tid = threadIdx.x;

    int j0 = cb*64 + tid;
    float4 cbx = (j0 < PRE_NMS) ? gboxes[(size_t)b*PRE_NMS + j0]
                                : make_float4(0.f,0.f,0.f,0.f);
    cx1[tid]=cbx.x; cy1[tid]=cbx.y; cx2[tid]=cbx.z; cy2[tid]=cbx.w;
    car[tid]=(cbx.z-cbx.x+1.0f)*(cbx.w-cbx.y+1.0f);
    __syncthreads();

    int i = rb*64 + tid;
    if (i >= PRE_NMS) return;
    float4 rbx = gboxes[(size_t)b*PRE_NMS + i];
    float ix1=rbx.x, iy1=rbx.y, ix2=rbx.z, iy2=rbx.w;
    float iarea=(ix2-ix1+1.0f)*(iy2-iy1+1.0f);

    ull bits = 0;
    #pragma unroll 16
    for (int k = 0; k < 64; ++k) {
        int j = cb*64 + k;
        float xx1 = fmaxf(ix1, cx1[k]);
        float yy1 = fmaxf(iy1, cy1[k]);
        float xx2 = fminf(ix2, cx2[k]);
        float yy2 = fminf(iy2, cy2[k]);
        float ww = fmaxf(xx2 - xx1 + 1.0f, 0.0f);
        float hh = fmaxf(yy2 - yy1 + 1.0f, 0.0f);
        float inter = ww * hh;
        float iou = inter / (iarea + car[k] - inter);
        if ((j > i) & (j < PRE_NMS) & (iou > NMS_T)) bits |= (1ull << k);
    }
    mask[(((size_t)b*MROWS + i) << 6) + cb] = bits;
}

// ---------------------------------------------------------------------------
// Kernel 4: greedy scan v3. 1 wave/image; window wi's 64 rows (32 KB,
// contiguous) are prefetched into LDS one window ahead (loads issued to regs
// before processing the current window, written to LDS after). Per-kept
// critical chain = one LDS broadcast read instead of a ~900-cycle HBM load.
// ---------------------------------------------------------------------------
__global__ __launch_bounds__(64) void scan_kernel(const ull* __restrict__ mask,
                                                  const float4* __restrict__ gboxes,
                                                  float* __restrict__ out) {
    __shared__ ull buf[2][64][ROWSTRIDE];   // 64 KB double-buffered window rows
    __shared__ int keep_idx[POST_NMS];
    int b = blockIdx.x;
    int lane = threadIdx.x;
    const ull* mbase = mask + ((size_t)b * MROWS << 6);

    ull supp = 0;
    if (lane == NWORDS-1) supp = 0xFFFFFFFF00000000ull;  // candidates >= 4000
    if (lane >= NWORDS)   supp = ~0ull;
    int kept = 0;
    bool done = false;
    int cur = 0;

    // synchronous prefetch of window 0
    {
        const ulonglong2* src = (const ulonglong2*)mbase;
        ulonglong2* d2 = (ulonglong2*)buf[0];
        #pragma unroll
        for (int m = 0; m < 32; ++m) d2[lane + (m << 6)] = src[lane + (m << 6)];
        __syncthreads();
    }

    for (int wi = 0; wi < NWORDS && !done; ++wi) {
        // issue next-window loads into registers (overlaps with processing)
        ulonglong2 pf[32];
        bool havepf = (wi + 1 < NWORDS);
        if (havepf) {
            const ulonglong2* src =
                (const ulonglong2*)(mbase + (((size_t)(wi+1) << 6) << 6));
            #pragma unroll
            for (int m = 0; m < 32; ++m) pf[m] = src[lane + (m << 6)];
        }

        // process current window out of LDS
        ull avail = ~__shfl(supp, wi);
        while (avail) {
            int bi = __builtin_ctzll(avail);
            int i = (wi << 6) + bi;
            if (lane == 0) keep_idx[kept] = i;
            ++kept;
            if (kept >= POST_NMS) { done = true; break; }
            ull w = buf[cur][bi][wi];                       // broadcast read
            ull r = (lane > wi) ? buf[cur][bi][lane] : 0;   // future-window supp
            supp |= r;
            avail &= ~w;
            avail &= ~(1ull << bi);
        }

        // land the prefetch, swap buffers
        if (havepf && !done) {
            ulonglong2* d2 = (ulonglong2*)buf[cur ^ 1];
            #pragma unroll
            for (int m = 0; m < 32; ++m) d2[lane + (m << 6)] = pf[m];
            __syncthreads();
            cur ^= 1;
        }
    }
    __syncthreads();

    for (int r = lane; r < POST_NMS; r += 64) {
        float4 bx = (r < kept) ? gboxes[(size_t)b*PRE_NMS + keep_idx[r]]
                               : make_float4(0.f,0.f,0.f,0.f);
        float* o = out + (size_t)(b*POST_NMS + r)*5;
        o[0]=(float)b; o[1]=bx.x; o[2]=bx.y; o[3]=bx.z; o[4]=bx.w;
    }
}

// ---------------------------------------------------------------------------
extern "C" void kernel_launch(void* const* d_in, const int* in_sizes, int n_in,
                              void* d_out, int out_size, void* d_ws, size_t ws_size,
                              hipStream_t stream) {
    (void)n_in; (void)out_size; (void)ws_size;
    const float* scores  = (const float*)d_in[0];
    const float* deltas  = (const float*)d_in[1];
    const float* im_info = (const float*)d_in[2];
    const float* anchors = (const float*)d_in[3];
    float* out = (float*)d_out;

    const int B = in_sizes[0] / (2*NA*HH*WW);   // = 2

    // ws layout: boxes4 | gboxes | keys | mask | hist   (~5.9 MB)
    float4* boxes4 = (float4*)d_ws;
    float4* gboxes = boxes4 + (size_t)B*NPROP;
    ull*    keys   = (ull*)(gboxes + (size_t)B*PRE_NMS);
    ull*    mask   = keys + (size_t)B*NPROP;
    uint32_t* hist = (uint32_t*)(mask + ((size_t)B*MROWS << 6));

    hipMemsetAsync(hist, 0, (size_t)B*65536*sizeof(uint32_t), stream);
    decode_hist<<<(B*NPROP + 255)/256, 256, 0, stream>>>(scores, deltas, im_info,
                                                         anchors, keys, boxes4, hist, B);
    select_sort_gather<<<B, 1024, 0, stream>>>(keys, hist, boxes4, gboxes);
    dim3 mgrid(NWORDS, NWORDS, B);
    mask_kernel<<<mgrid, 64, 0, stream>>>(gboxes, mask);
    scan_kernel<<<B, 64, 0, stream>>>(mask, gboxes, out);
}

// Round 9
// 249.780 us; speedup vs baseline: 4.3795x; 1.0282x over previous
//
#include <hip/hip_runtime.h>
#include <stdint.h>

#define NA 9
#define HH 50
#define WW 50
#define NPROP (HH*WW*NA)      // 22500
#define PRE_NMS 4000
#define POST_NMS 300
#define NWORDS 63             // ceil(4000/64) suppression words per row
#define ROWSTRIDE 64          // mask row stride in u64 words
#define MROWS 4032            // padded rows per image (63 windows * 64)
#define SELN 8192             // compaction capacity (top-4000 + threshold-bucket slack)
#define NMS_T 0.7f
#define FSTRIDE 16.0f

typedef unsigned long long ull;

__device__ __forceinline__ uint32_t f32_ord(float s) {
    uint32_t u = __float_as_uint(s);
    return (u & 0x80000000u) ? ~u : (u | 0x80000000u);
}

// ---------------------------------------------------------------------------
// Kernel 1: decode boxes + build keys + histogram of top-16 key bits.
// ---------------------------------------------------------------------------
__global__ void decode_hist(const float* __restrict__ scores,
                            const float* __restrict__ deltas,
                            const float* __restrict__ im_info,
                            const float* __restrict__ anchors,
                            ull* __restrict__ keys,
                            float4* __restrict__ boxes4,
                            uint32_t* __restrict__ hist, int B) {
    int t = blockIdx.x * blockDim.x + threadIdx.x;
    if (t >= B * NPROP) return;
    int b = t / NPROP;
    int i = t % NPROP;

    int a   = i % NA;
    int pos = i / NA;          // h*W + w
    int w   = pos % WW;
    int h   = pos / WW;

    float score = scores[((size_t)b*2*NA + NA + a)*(HH*WW) + pos];
    ull key = ((ull)f32_ord(score) << 32) | (ull)(0xFFFFFFFFu - (uint32_t)i);
    keys[t] = key;
    atomicAdd(&hist[((uint32_t)b << 16) | (uint32_t)(key >> 48)], 1u);

    float ax1 = anchors[a*4+0], ay1 = anchors[a*4+1];
    float ax2 = anchors[a*4+2], ay2 = anchors[a*4+3];
    float sx = (float)w * FSTRIDE, sy = (float)h * FSTRIDE;
    float x1 = ax1 + sx, y1 = ay1 + sy, x2 = ax2 + sx, y2 = ay2 + sy;
    float bw = x2 - x1 + 1.0f;
    float bh = y2 - y1 + 1.0f;
    float cx = x1 + 0.5f * bw;
    float cy = y1 + 0.5f * bh;

    const float* dp = deltas + (size_t)b*4*NA*(HH*WW);
    float dx = dp[(4*a+0)*(HH*WW)+pos];
    float dy = dp[(4*a+1)*(HH*WW)+pos];
    float dw = dp[(4*a+2)*(HH*WW)+pos];
    float dh = dp[(4*a+3)*(HH*WW)+pos];

    float pcx = dx * bw + cx;
    float pcy = dy * bh + cy;
    float pw  = expf(dw) * bw;
    float ph  = expf(dh) * bh;

    float wmax = im_info[b*3+1] - 1.0f;
    float hmax = im_info[b*3+0] - 1.0f;
    float px1 = fminf(fmaxf(pcx - 0.5f*pw, 0.0f), wmax);
    float py1 = fminf(fmaxf(pcy - 0.5f*ph, 0.0f), hmax);
    float px2 = fminf(fmaxf(pcx + 0.5f*pw, 0.0f), wmax);
    float py2 = fminf(fmaxf(pcy + 0.5f*ph, 0.0f), hmax);

    boxes4[t] = make_float4(px1, py1, px2, py2);
}

// ---------------------------------------------------------------------------
// Kernel 2: one block per image. Find the 16-bit threshold bucket from the
// histogram (coarse Hillis-Steele cumulative-from-top + fine serial), then
// compact all keys in buckets >= threshold to global ckeys (M in
// [4000, ~4100] for random scores; SELN=8192 slack), zero-pad the tail,
// store M.
// ---------------------------------------------------------------------------
__global__ __launch_bounds__(1024) void compact_kernel(
        const ull* __restrict__ keys,
        const uint32_t* __restrict__ hist,
        ull* __restrict__ ckeys,
        int* __restrict__ mcount) {
    __shared__ int sA[1024], sB[1024]; // coarse sums + scan ping-pong
    __shared__ int nfine[64];
    __shared__ int sSeg, aboveC, thr, lcount;
    int img = blockIdx.x, tid = threadIdx.x;
    const uint32_t* h = hist + ((uint32_t)img << 16);

    // --- Phase A: coarse per-64-bucket sums (vectorized uint4 loads) ---
    {
        const uint4* h4 = (const uint4*)h;
        uint32_t s = 0;
        #pragma unroll
        for (int u = 0; u < 16; ++u) {
            uint4 v = h4[(tid << 4) | u];
            s += v.x + v.y + v.z + v.w;
        }
        sA[tid] = (int)s;
    }
    __syncthreads();
    // cumulative-from-top: cft[t] = sum_{u>=t} coarse[u]
    int* curp = sA; int* nxtp = sB;
    for (int d = 1; d < 1024; d <<= 1) {
        int v = curp[tid] + ((tid + d < 1024) ? curp[tid + d] : 0);
        nxtp[tid] = v;
        __syncthreads();
        int* tmp = curp; curp = nxtp; nxtp = tmp;
    }
    {
        int cftS  = curp[tid];
        int cftS1 = (tid < 1023) ? curp[tid + 1] : 0;
        if (cftS >= PRE_NMS && cftS1 < PRE_NMS) { sSeg = tid; aboveC = cftS1; }
    }
    __syncthreads();
    if (tid < 64) nfine[tid] = (int)h[(sSeg << 6) | tid];
    __syncthreads();
    if (tid == 0) {
        int cum = aboveC;          // count of keys in buckets > current
        int t = sSeg << 6;
        for (int w = 63; w >= 0; --w) {
            int nc = cum + nfine[w];
            if (nc >= PRE_NMS) { t = (sSeg << 6) | w; break; }
            cum = nc;
        }
        thr = t;
        lcount = 0;
    }
    __syncthreads();

    // --- Phase B: compact keys with bucket >= thr into global ckeys ---
    ull* ck = ckeys + (size_t)img * SELN;
    {
        const ull* kb = keys + (size_t)img * NPROP;
        int th = thr;
        for (int i = tid; i < NPROP; i += 1024) {
            ull key = kb[i];
            if ((int)(key >> 48) >= th) {
                int p = atomicAdd(&lcount, 1);
                if (p < SELN) ck[p] = key;
            }
        }
    }
    __syncthreads();
    int M = lcount; if (M > SELN) M = SELN;
    if (tid == 0) mcount[img] = M;
    for (int e = M + tid; e < SELN; e += 1024) ck[e] = 0ull;
}

// ---------------------------------------------------------------------------
// Kernel 3: rank-by-count scatter. Keys unique => rank = #{keys > my} is an
// exact descending-sort permutation. Grid (SELN/256, B) x 256: each block
// stages the M compacted keys in LDS (broadcast reads, conflict-free), each
// thread ranks one key and scatters its box to gboxes[rank] if rank<4000.
// ---------------------------------------------------------------------------
__global__ __launch_bounds__(256) void rank_scatter(
        const ull* __restrict__ ckeys,
        const int* __restrict__ mcount,
        const float4* __restrict__ boxes4,
        float4* __restrict__ gboxes) {
    __shared__ ull lk[SELN];
    __shared__ int sM;
    int img = blockIdx.y, rb = blockIdx.x, tid = threadIdx.x;
    if (tid == 0) sM = mcount[img];
    __syncthreads();
    int M = sM;
    if (rb * 256 >= M) return;                 // whole block beyond last candidate
    int Ms = (M + 255) & ~255;                 // staged length (zero-padded)

    const ull* kb = ckeys + (size_t)img * SELN;
    for (int e = tid; e < Ms; e += 256) lk[e] = (e < M) ? kb[e] : 0ull;
    __syncthreads();

    int row = rb * 256 + tid;
    if (row >= M) return;
    ull my = lk[row];

    int rank = 0;
    #pragma unroll 8
    for (int e = 0; e < Ms; ++e) rank += (lk[e] > my) ? 1 : 0;

    if (rank < PRE_NMS) {
        uint32_t idx = 0xFFFFFFFFu - (uint32_t)(my & 0xFFFFFFFFull);
        gboxes[(size_t)img*PRE_NMS + rank] = boxes4[(size_t)img*NPROP + idx];
    }
}

// ---------------------------------------------------------------------------
// Kernel 4: suppression bit-matrix (only j>i bits; words cb>=rb written).
// ---------------------------------------------------------------------------
__global__ __launch_bounds__(64) void mask_kernel(const float4* __restrict__ gboxes,
                                                  ull* __restrict__ mask) {
    int rb = blockIdx.x, cb = blockIdx.y, b = blockIdx.z;
    if (cb < rb) return;
    __shared__ float cx1[64], cy1[64], cx2[64], cy2[64], car[64];
    int tid = threadIdx.x;

    int j0 = cb*64 + tid;
    float4 cbx = (j0 < PRE_NMS) ? gboxes[(size_t)b*PRE_NMS + j0]
                                : make_float4(0.f,0.f,0.f,0.f);
    cx1[tid]=cbx.x; cy1[tid]=cbx.y; cx2[tid]=cbx.z; cy2[tid]=cbx.w;
    car[tid]=(cbx.z-cbx.x+1.0f)*(cbx.w-cbx.y+1.0f);
    __syncthreads();

    int i = rb*64 + tid;
    if (i >= PRE_NMS) return;
    float4 rbx = gboxes[(size_t)b*PRE_NMS + i];
    float ix1=rbx.x, iy1=rbx.y, ix2=rbx.z, iy2=rbx.w;
    float iarea=(ix2-ix1+1.0f)*(iy2-iy1+1.0f);

    ull bits = 0;
    #pragma unroll 16
    for (int k = 0; k < 64; ++k) {
        int j = cb*64 + k;
        float xx1 = fmaxf(ix1, cx1[k]);
        float yy1 = fmaxf(iy1, cy1[k]);
        float xx2 = fminf(ix2, cx2[k]);
        float yy2 = fminf(iy2, cy2[k]);
        float ww = fmaxf(xx2 - xx1 + 1.0f, 0.0f);
        float hh = fmaxf(yy2 - yy1 + 1.0f, 0.0f);
        float inter = ww * hh;
        float iou = inter / (iarea + car[k] - inter);
        if ((j > i) & (j < PRE_NMS) & (iou > NMS_T)) bits |= (1ull << k);
    }
    mask[(((size_t)b*MROWS + i) << 6) + cb] = bits;
}

// ---------------------------------------------------------------------------
// Kernel 5: greedy scan with per-window LDS prefetch (serial chain = LDS
// broadcast reads; next window's 32KB prefetched into regs during processing).
// ---------------------------------------------------------------------------
__global__ __launch_bounds__(64) void scan_kernel(const ull* __restrict__ mask,
                                                  const float4* __restrict__ gboxes,
                                                  float* __restrict__ out) {
    __shared__ ull buf[2][64][ROWSTRIDE];   // 64 KB double-buffered window rows
    __shared__ int keep_idx[POST_NMS];
    int b = blockIdx.x;
    int lane = threadIdx.x;
    const ull* mbase = mask + ((size_t)b * MROWS << 6);

    ull supp = 0;
    if (lane == NWORDS-1) supp = 0xFFFFFFFF00000000ull;  // candidates >= 4000
    if (lane >= NWORDS)   supp = ~0ull;
    int kept = 0;
    bool done = false;
    int cur = 0;

    // synchronous prefetch of window 0
    {
        const ulonglong2* src = (const ulonglong2*)mbase;
        ulonglong2* d2 = (ulonglong2*)buf[0];
        #pragma unroll
        for (int m = 0; m < 32; ++m) d2[lane + (m << 6)] = src[lane + (m << 6)];
        __syncthreads();
    }

    for (int wi = 0; wi < NWORDS && !done; ++wi) {
        // issue next-window loads into registers (overlaps with processing)
        ulonglong2 pf[32];
        bool havepf = (wi + 1 < NWORDS);
        if (havepf) {
            const ulonglong2* src =
                (const ulonglong2*)(mbase + (((size_t)(wi+1) << 6) << 6));
            #pragma unroll
            for (int m = 0; m < 32; ++m) pf[m] = src[lane + (m << 6)];
        }

        // process current window out of LDS
        ull avail = ~__shfl(supp, wi);
        while (avail) {
            int bi = __builtin_ctzll(avail);
            int i = (wi << 6) + bi;
            if (lane == 0) keep_idx[kept] = i;
            ++kept;
            if (kept >= POST_NMS) { done = true; break; }
            ull w = buf[cur][bi][wi];                       // broadcast read
            ull r = (lane > wi) ? buf[cur][bi][lane] : 0;   // future-window supp
            supp |= r;
            avail &= ~w;
            avail &= ~(1ull << bi);
        }

        // land the prefetch, swap buffers
        if (havepf && !done) {
            ulonglong2* d2 = (ulonglong2*)buf[cur ^ 1];
            #pragma unroll
            for (int m = 0; m < 32; ++m) d2[lane + (m << 6)] = pf[m];
            __syncthreads();
            cur ^= 1;
        }
    }
    __syncthreads();

    for (int r = lane; r < POST_NMS; r += 64) {
        float4 bx = (r < kept) ? gboxes[(size_t)b*PRE_NMS + keep_idx[r]]
                               : make_float4(0.f,0.f,0.f,0.f);
        float* o = out + (size_t)(b*POST_NMS + r)*5;
        o[0]=(float)b; o[1]=bx.x; o[2]=bx.y; o[3]=bx.z; o[4]=bx.w;
    }
}

// ---------------------------------------------------------------------------
extern "C" void kernel_launch(void* const* d_in, const int* in_sizes, int n_in,
                              void* d_out, int out_size, void* d_ws, size_t ws_size,
                              hipStream_t stream) {
    (void)n_in; (void)out_size; (void)ws_size;
    const float* scores  = (const float*)d_in[0];
    const float* deltas  = (const float*)d_in[1];
    const float* im_info = (const float*)d_in[2];
    const float* anchors = (const float*)d_in[3];
    float* out = (float*)d_out;

    const int B = in_sizes[0] / (2*NA*HH*WW);   // = 2

    // ws layout: boxes4 | gboxes | keys | ckeys | mask | hist | mcount
    float4* boxes4 = (float4*)d_ws;
    float4* gboxes = boxes4 + (size_t)B*NPROP;
    ull*    keys   = (ull*)(gboxes + (size_t)B*PRE_NMS);
    ull*    ckeys  = keys + (size_t)B*NPROP;
    ull*    mask   = ckeys + (size_t)B*SELN;
    uint32_t* hist = (uint32_t*)(mask + ((size_t)B*MROWS << 6));
    int*    mcount = (int*)(hist + (size_t)B*65536);

    hipMemsetAsync(hist, 0, (size_t)B*65536*sizeof(uint32_t), stream);
    decode_hist<<<(B*NPROP + 255)/256, 256, 0, stream>>>(scores, deltas, im_info,
                                                         anchors, keys, boxes4, hist, B);
    compact_kernel<<<B, 1024, 0, stream>>>(keys, hist, ckeys, mcount);
    dim3 rgrid(SELN/256, B);
    rank_scatter<<<rgrid, 256, 0, stream>>>(ckeys, mcount, boxes4, gboxes);
    dim3 mgrid(NWORDS, NWORDS, B);
    mask_kernel<<<mgrid, 64, 0, stream>>>(gboxes, mask);
    scan_kernel<<<B, 64, 0, stream>>>(mask, gboxes, out);
}